// Round 1
// baseline (953.612 us; speedup 1.0000x reference)
//
#include <hip/hip_runtime.h>

// Problem constants
#define BATCH   16
#define CIN     256
#define EDIM    256
#define HW      4096            // 64*64
#define NPIX    65536           // BATCH*HW
#define RREAL   365
#define RPAD    368             // 23 chunks of 16
#define NCHUNK  23
#define OUTPLANE 23920640       // B*R*HW
#define ESTRIDE 264             // LDS emb row stride in shorts (256 + 8 pad: kills bank aliasing)

typedef __attribute__((ext_vector_type(8))) short short8;
typedef __attribute__((ext_vector_type(4))) float f32x4;

__device__ __forceinline__ unsigned short f2bf(float f) {
    union { float f; unsigned u; } v; v.f = f;
    unsigned r = v.u + 0x7fffu + ((v.u >> 16) & 1u);   // RNE
    return (unsigned short)(r >> 16);
}

// ---------------- K1: reps -> 3 bf16 planes [RPAD][256]  (+ conv_w -> bf16) ----------------
// Wave-cooperative GEMV: lanes span k (coalesced 1KB negw rows), shfl-reduce per output row.
__global__ __launch_bounds__(256) void k_reps(const float* __restrict__ reps,
                                              const float* __restrict__ negw,
                                              const float* __restrict__ negb,
                                              const float* __restrict__ convw,
                                              unsigned short* __restrict__ wbf,
                                              unsigned short* __restrict__ rp,
                                              unsigned short* __restrict__ rn0,
                                              unsigned short* __restrict__ rn1) {
    int r = blockIdx.x;
    int t = threadIdx.x;
    if (r < 256) wbf[r*256 + t] = f2bf(convw[r*256 + t]);   // fold former k_cvt_w
    if (r >= RREAL) {           // zero-pad rows 365..367
        rp[r*256 + t] = 0; rn0[r*256 + t] = 0; rn1[r*256 + t] = 0;
        return;
    }
    __shared__ __align__(16) float sa[256];    // |reps_r|
    __shared__ float outo[512];                // neg_offset + bias, rows 0..511
    __shared__ float red[8];
    float rv = reps[r*256 + t];
    float av = fabsf(rv);
    sa[t] = av;
    __syncthreads();
    int wid = t >> 6, lane = t & 63;
    const f32x4* a4 = (const f32x4*)sa;
    f32x4 a = a4[lane];
    // each wave computes 128 of the 512 output rows; negw row read coalesced (1KB contiguous)
    #pragma unroll 4
    for (int i = 0; i < 128; i++) {
        int e = wid*128 + i;
        f32x4 wv = *(const f32x4*)(negw + (size_t)e*256 + lane*4);
        float p = wv[0]*a[0] + wv[1]*a[1] + wv[2]*a[2] + wv[3]*a[3];
        #pragma unroll
        for (int off = 32; off; off >>= 1) p += __shfl_xor(p, off);
        if (lane == 0) outo[e] = p + negb[e];
    }
    __syncthreads();
    float sgn = (rv > 0.f) ? 1.f : ((rv < 0.f) ? -1.f : 0.f);
    float v0 = (outo[t] + av) * sgn;
    float v1 = (outo[256 + t] + av) * sgn;
    float s0 = v0*v0, s1 = v1*v1;
    #pragma unroll
    for (int off = 32; off; off >>= 1) { s0 += __shfl_xor(s0, off); s1 += __shfl_xor(s1, off); }
    if ((t & 63) == 0) { red[wid] = s0; red[4 + wid] = s1; }
    __syncthreads();
    float t0 = red[0] + red[1] + red[2] + red[3];
    float t1 = red[4] + red[5] + red[6] + red[7];
    float i0 = 1.f / fmaxf(sqrtf(t0), 1e-12f);
    float i1 = 1.f / fmaxf(sqrtf(t1), 1e-12f);
    rp [r*256 + t] = f2bf(rv);
    rn0[r*256 + t] = f2bf(v0 * i0);
    rn1[r*256 + t] = f2bf(v1 * i1);
}

// ---------------- K2: FUSED conv1x1+L2norm -> (LDS) -> distances + probs ----------------
// Phase 1 (conv): A = x tile (M=16 px), B = conv_w^T. emb bf16 goes to LDS (transposed to
//                 e-contiguous-per-lane layout), never to HBM.
// Phase 2 (main): A = emb (M=16 px), B = reps chunk (N=16 r). C-row = px, so each lane's
//                 f32x4 acc = 4 CONSECUTIVE pixels at one r -> all stores are float4.
__global__ __launch_bounds__(256) void k_fused(const float* __restrict__ x,
                                               const unsigned short* __restrict__ wbf,
                                               const float* __restrict__ convb,
                                               const unsigned short* __restrict__ rp,
                                               const unsigned short* __restrict__ rn0,
                                               const unsigned short* __restrict__ rn1,
                                               float* __restrict__ oCls,
                                               float* __restrict__ oClsNeg,
                                               float* __restrict__ oDist,
                                               float* __restrict__ oDneg,
                                               float* __restrict__ oPori,
                                               float* __restrict__ sumij) {
    __shared__ unsigned short elds[4][16][ESTRIDE];   // 33,792 B
    int wave = threadIdx.x >> 6, lane = threadIdx.x & 63;
    int l15 = lane & 15, quad = lane >> 4;
    int px0 = blockIdx.x * 64 + wave * 16;
    int b = px0 >> 12, hw0 = px0 & 4095;
    const float* xb = x + (size_t)b * CIN * HW;
    int hwa = hw0 + l15;

    // ---- phase 1: conv + bias + L2 norm, result to LDS ----
    f32x4 acc[16];
    #pragma unroll
    for (int et = 0; et < 16; et++) acc[et] = (f32x4){0.f, 0.f, 0.f, 0.f};
    for (int k0 = 0; k0 < 8; k0++) {
        int c0 = k0 * 32 + quad * 8;
        short8 af;
        #pragma unroll
        for (int j = 0; j < 8; j++) {
            float xv = xb[(size_t)(c0 + j) * HW + hwa];
            ((unsigned short*)&af)[j] = f2bf(xv);
        }
        #pragma unroll
        for (int et = 0; et < 16; et++) {
            short8 bf = *(const short8*)(wbf + (size_t)(et*16 + l15) * 256 + k0*32 + quad*8);
            acc[et] = __builtin_amdgcn_mfma_f32_16x16x32_bf16(af, bf, acc[et], 0, 0, 0);
        }
    }
    float cb[16];
    #pragma unroll
    for (int et = 0; et < 16; et++) cb[et] = convb[et*16 + l15];
    #pragma unroll
    for (int reg = 0; reg < 4; reg++) {
        int pl = quad * 4 + reg;               // local px row
        float v[16]; float s = 0.f;
        #pragma unroll
        for (int et = 0; et < 16; et++) {
            float vv = acc[et][reg] + cb[et];
            v[et] = vv; s += vv * vv;
        }
        s += __shfl_xor(s, 1); s += __shfl_xor(s, 2);
        s += __shfl_xor(s, 4); s += __shfl_xor(s, 8);
        float inv = 1.f / fmaxf(sqrtf(s), 1e-12f);
        #pragma unroll
        for (int et = 0; et < 16; et++)
            elds[wave][pl][et*16 + l15] = f2bf(v[et] * inv);
    }
    __syncthreads();   // order LDS writes (transpose) before frag reads

    // ---- phase 2: distances for all 368 (padded) reps rows ----
    short8 ef[8];
    #pragma unroll
    for (int k0 = 0; k0 < 8; k0++)
        ef[k0] = *(const short8*)&elds[wave][l15][k0*32 + quad*8];

    size_t obase = (size_t)b * RREAL * HW;
    int hwq = hw0 + quad * 4;
    size_t rowb = obase        + ((size_t)l15 << 12) + hwq;   // oDist/oPori/oClsNeg/oCls row base
    size_t idnb = (obase << 1) + ((size_t)l15 << 13) + hwq;   // oDneg base (2 modes interleaved)
    f32x4 sumP = (f32x4){0.f, 0.f, 0.f, 0.f};

    for (int ch = 0; ch < NCHUNK; ch++) {
        int r = ch * 16 + l15;                 // this lane's reps row
        size_t rrow = (size_t)r * 256 + quad * 8;
        f32x4 aP  = (f32x4){0.f,0.f,0.f,0.f};
        f32x4 aN0 = (f32x4){0.f,0.f,0.f,0.f};
        f32x4 aN1 = (f32x4){0.f,0.f,0.f,0.f};
        #pragma unroll
        for (int k0 = 0; k0 < 8; k0++) {
            short8 fp = *(const short8*)(rp  + rrow + k0*32);
            short8 f0 = *(const short8*)(rn0 + rrow + k0*32);
            short8 f1 = *(const short8*)(rn1 + rrow + k0*32);
            aP  = __builtin_amdgcn_mfma_f32_16x16x32_bf16(ef[k0], fp, aP , 0, 0, 0);
            aN0 = __builtin_amdgcn_mfma_f32_16x16x32_bf16(ef[k0], f0, aN0, 0, 0, 0);
            aN1 = __builtin_amdgcn_mfma_f32_16x16x32_bf16(ef[k0], f1, aN1, 0, 0, 0);
        }
        f32x4 vD, vPori, vCneg, vCls, vDn0, vDn1;
        #pragma unroll
        for (int c = 0; c < 4; c++) {
            float d2 = fmaxf(2.f - 2.f * aP [c], 0.f);
            float e0 = fmaxf(2.f - 2.f * aN0[c], 0.f);
            float e1 = fmaxf(2.f - 2.f * aN1[c], 0.f);
            float d   = sqrtf(d2);
            float dn0 = sqrtf(e0);
            float dn1 = sqrtf(e1);
            vD[c]    = d;
            vDn0[c]  = dn0;
            vDn1[c]  = dn1;
            vPori[c] = __expf(-2.f * d2);
            float pn0 = __expf(-2.f * e0);
            float pn1 = __expf(-2.f * e1);
            vCneg[c] = fmaxf(pn0, pn1);
            float dnmin = fminf(dn0, dn1);
            float tt = fmaf(-0.3f, dnmin, d + 0.6f);   // d + 0.3*(2 - dnmin)
            vCls[c]  = __expf(-2.f * tt * tt);
        }
        if (r < RREAL) {
            size_t row = rowb + ((size_t)ch << 16);    // += 16*4096 floats per chunk
            *(f32x4*)(oDist   + row) = vD;
            *(f32x4*)(oPori   + row) = vPori;
            *(f32x4*)(oClsNeg + row) = vCneg;
            *(f32x4*)(oCls    + row) = vCls;           // numerator; normalized in k_div
            size_t idn = idnb + ((size_t)ch << 17);
            *(f32x4*)(oDneg + idn)      = vDn0;
            *(f32x4*)(oDneg + idn + HW) = vDn1;
            sumP += vCls;
        }
    }
    // reduce over the 16 r-lanes -> full sum over r for each of this quad's 4 px
    #pragma unroll
    for (int off = 1; off <= 8; off <<= 1) {
        sumP[0] += __shfl_xor(sumP[0], off);
        sumP[1] += __shfl_xor(sumP[1], off);
        sumP[2] += __shfl_xor(sumP[2], off);
        sumP[3] += __shfl_xor(sumP[3], off);
    }
    if (l15 == 0)
        *(f32x4*)(sumij + px0 + quad * 4) = sumP;      // lanes 0/16/32/48 -> 64B contiguous
}

// ---------------- K3: cls_score normalization (no integer division) ----------------
__global__ __launch_bounds__(256) void k_div(float* __restrict__ oCls,
                                             const float* __restrict__ sumij) {
    int bb = blockIdx.y;
    size_t off = (size_t)blockIdx.x * 1024 + threadIdx.x * 4;
    int hw = (int)(off & 4095);
    float* p = oCls + (size_t)bb * ((size_t)RREAL * HW) + off;
    f32x4 v = *(f32x4*)p;
    f32x4 s = *(const f32x4*)(sumij + bb * HW + hw);
    v[0] /= s[0]; v[1] /= s[1]; v[2] /= s[2]; v[3] /= s[3];
    *(f32x4*)p = v;
}

extern "C" void kernel_launch(void* const* d_in, const int* in_sizes, int n_in,
                              void* d_out, int out_size, void* d_ws, size_t ws_size,
                              hipStream_t stream) {
    const float* x      = (const float*)d_in[0];
    const float* conv_w = (const float*)d_in[1];
    const float* conv_b = (const float*)d_in[2];
    const float* reps   = (const float*)d_in[3];
    const float* neg_w  = (const float*)d_in[4];
    const float* neg_b  = (const float*)d_in[5];
    float* out = (float*)d_out;

    // workspace layout (~1 MB; emb round-trip eliminated)
    char* ws = (char*)d_ws;
    unsigned short* rp  = (unsigned short*)ws;                 // RPAD*256*2 = 188,416 B each
    unsigned short* rn0 = rp  + RPAD * 256;
    unsigned short* rn1 = rn0 + RPAD * 256;
    unsigned short* wbf = rn1 + RPAD * 256;                    // 256*256*2 = 131,072 B
    float* sumij = (float*)(ws + 3 * RPAD * 256 * 2 + 65536 * 2);   // NPIX*4 = 262,144 B

    float* oCls    = out;
    float* oClsNeg = out + (size_t)OUTPLANE;
    float* oDist   = out + (size_t)OUTPLANE * 2;
    float* oDneg   = out + (size_t)OUTPLANE * 3;
    float* oPori   = out + (size_t)OUTPLANE * 5;

    k_reps <<<RPAD, 256, 0, stream>>>(reps, neg_w, neg_b, conv_w, wbf, rp, rn0, rn1);
    k_fused<<<NPIX / 64, 256, 0, stream>>>(x, wbf, conv_b, rp, rn0, rn1,
                                           oCls, oClsNeg, oDist, oDneg, oPori, sumij);
    k_div  <<<dim3(RREAL * HW / 1024, BATCH), 256, 0, stream>>>(oCls, sumij);
}